// Round 3
// baseline (445.803 us; speedup 1.0000x reference)
//
#include <hip/hip_runtime.h>

// ---------------------------------------------------------------------------
// 2-layer GCN on MI355X.
//   h   = relu( Dinv (A+I) Dinv (z @ W1) + b1 )
//   out =       Dinv (A+I) Dinv (h @ W2) + b2
// R12 == R11 resubmitted (round-2 bench was an infra failure: container died
// before producing a verdict; audit found no fault vector in the kernel).
// R11: XCD column-sliced aggregation. Diagnosis: agg is bound by
// outstanding-miss capacity x latency (VALU 37%, L2-miss BW 3.4 TB/s, nothing
// saturated; FETCH ~= 8 XCDs x full 25.6MB array). Fix: feature dim split
// into 32-col chunks stored CHUNK-MAJOR ([chunk][node][32], contiguous
// 3.2MB slice per chunk); chunk pinned to XCD via blockIdx%8 so each XCD's
// random gathers hit its own L2-resident slice. 8 lanes cover a 64B
// chunk-row -> one wave instr gathers 8 independent edges. edata re-read
// per chunk-pass uses nontemporal loads to keep the slice resident.
// GEMMs write chunk-major C; gemm2 reads chunk-major A (BK=32 == chunk w).
// 8 dispatches: memset, prep, scan, fill, gemm1, agg1, gemm2, agg2.
// ---------------------------------------------------------------------------

#define N_NODES 50000
#define N_EDGES 800000
#define D_IN    256
#define D_HID   256
#define D_OUT   128

typedef unsigned int uint32;
typedef unsigned short u16;

typedef __attribute__((ext_vector_type(8))) short bf16x8;   // MFMA A/B frag
typedef __attribute__((ext_vector_type(4))) float f32x4;    // MFMA C/D frag

__device__ __forceinline__ u16 f2bf_rne(float f) {
    union { float f; uint32 u; } c; c.f = f;
    uint32 u = c.u;
    u += 0x7FFFu + ((u >> 16) & 1u);
    return (u16)(u >> 16);
}
__device__ __forceinline__ float bf_lo(uint32 p) {
    union { uint32 u; float f; } c; c.u = p << 16; return c.f;
}
__device__ __forceinline__ float bf_hi(uint32 p) {
    union { uint32 u; float f; } c; c.u = p & 0xFFFF0000u; return c.f;
}

// ---------------- fused independent prep ----------------
// z->bf16, W1^T bf16, W2^T bf16, degree atomics WITH rank capture.

__global__ __launch_bounds__(256) void prep_kernel(const float* __restrict__ z,
                                                   const int* __restrict__ dst,
                                                   const float* __restrict__ W1,
                                                   const float* __restrict__ W2,
                                                   u16* __restrict__ zb,
                                                   u16* __restrict__ w1t,
                                                   u16* __restrict__ w2t,
                                                   int* __restrict__ cnt,
                                                   int* __restrict__ rank) {
    const int g = blockIdx.x * 256 + threadIdx.x;
    const int GT = gridDim.x * 256;

    for (int c = g; c < N_NODES * D_IN / 8; c += GT) {
        int i = c * 8;
        float4 a = *(const float4*)(z + i);
        float4 d = *(const float4*)(z + i + 4);
        uint4 pk;
        pk.x = (uint32)f2bf_rne(a.x) | ((uint32)f2bf_rne(a.y) << 16);
        pk.y = (uint32)f2bf_rne(a.z) | ((uint32)f2bf_rne(a.w) << 16);
        pk.z = (uint32)f2bf_rne(d.x) | ((uint32)f2bf_rne(d.y) << 16);
        pk.w = (uint32)f2bf_rne(d.z) | ((uint32)f2bf_rne(d.w) << 16);
        *(uint4*)(zb + i) = pk;
    }
    for (int idx = g; idx < D_IN * D_HID + D_HID * D_OUT; idx += GT) {
        if (idx < D_IN * D_HID) {
            int nrow = idx >> 8, kcol = idx & 255;
            w1t[idx] = f2bf_rne(W1[kcol * D_HID + nrow]);
        } else {
            int j = idx - D_IN * D_HID;
            int nrow = j >> 8, kcol = j & 255;
            w2t[j] = f2bf_rne(W2[kcol * D_OUT + nrow]);
        }
    }
    for (int i = g; i < N_EDGES; i += GT)
        rank[i] = atomicAdd(&cnt[dst[i]], 1);
}

// ---------------- single-block vectorized scan ----------------

__global__ __launch_bounds__(1024) void scan_kernel(const int* __restrict__ cnt,
                                                    float* __restrict__ dinv,
                                                    int* __restrict__ row_ptr, int n) {
    __shared__ int wtot[16];
    __shared__ int carry_s;
    const int t = threadIdx.x;
    const int lane = t & 63, w = t >> 6;
    if (t == 0) carry_s = 0;
    __syncthreads();

    const int n4 = n >> 2;
    for (int base = 0; base < n4; base += 1024) {
        int i4 = base + t;
        int4 v = make_int4(0, 0, 0, 0);
        if (i4 < n4) v = ((const int4*)cnt)[i4];
        int s = v.x + v.y + v.z + v.w;
        int x = s;
        #pragma unroll
        for (int off = 1; off < 64; off <<= 1) {
            int u = __shfl_up(x, off, 64);
            if (lane >= off) x += u;
        }
        if (lane == 63) wtot[w] = x;
        __syncthreads();

        int wbase = 0;
        #pragma unroll
        for (int j = 0; j < 16; ++j) if (j < w) wbase += wtot[j];
        int excl = carry_s + wbase + x - s;
        if (i4 < n4) {
            int4 rp;
            rp.x = excl;
            rp.y = rp.x + v.x;
            rp.z = rp.y + v.y;
            rp.w = rp.z + v.z;
            ((int4*)row_ptr)[i4] = rp;
            float4 dv;
            dv.x = rsqrtf((float)(v.x + 1));
            dv.y = rsqrtf((float)(v.y + 1));
            dv.z = rsqrtf((float)(v.z + 1));
            dv.w = rsqrtf((float)(v.w + 1));
            ((float4*)dinv)[i4] = dv;
        }
        __syncthreads();
        if (t == 0) {
            int tot = 0;
            #pragma unroll
            for (int j = 0; j < 16; ++j) tot += wtot[j];
            carry_s += tot;
        }
        __syncthreads();
    }
    if (t == 0) row_ptr[n] = carry_s;
}

// ---------------- atomic-free CSR fill: packed (col, weight) ----------------

__global__ void fill_kernel(const int* __restrict__ src, const int* __restrict__ dst,
                            const int* __restrict__ rank, const int* __restrict__ row_ptr,
                            const float* __restrict__ dinv,
                            int2* __restrict__ edata, int n_edges) {
    int i = blockIdx.x * blockDim.x + threadIdx.x;
    if (i < n_edges) {
        int s = src[i], d = dst[i];
        float w = dinv[s] * dinv[d];
        edata[row_ptr[d] + rank[i]] = make_int2(s, __float_as_int(w));
    }
}

// ---------------- bf16 MFMA GEMM (C chunk-major; A row- or chunk-major) ----

template <int NT, bool ACH>
__global__ __launch_bounds__(256, 4) void gemm_bf16_kernel(const u16* __restrict__ A,
                                                           const u16* __restrict__ BT,
                                                           u16* __restrict__ C, int M) {
    const int K = 256;
    __shared__ short As[128 * 32];
    __shared__ short Bs[128 * 32];

    const int m0 = blockIdx.x * 128;
    const int n0 = blockIdx.y * 128;
    const int t  = threadIdx.x;
    const int w  = t >> 6;
    const int lane = t & 63;
    const int lm = lane & 15;
    const int lq = lane >> 4;
    const int wm = w & 1;
    const int wn = w >> 1;

    f32x4 acc[4][4] = {};

    for (int k0 = 0; k0 < K; k0 += 32) {
        #pragma unroll
        for (int j = 0; j < 2; ++j) {
            int c = w * 128 + j * 64 + lane;
            int row = c >> 2;
            int kc = k0 + (c & 3) * 8;
            int gm = m0 + row; if (gm >= M) gm = M - 1;
            const u16* gpa;
            if constexpr (ACH)
                gpa = A + (size_t)(kc >> 5) * (size_t)M * 32 + (size_t)gm * 32 + (kc & 31);
            else
                gpa = A + (size_t)gm * K + kc;
            const u16* gpb = BT + (size_t)(n0 + row) * K + kc;
            __builtin_amdgcn_global_load_lds(
                (const __attribute__((address_space(1))) void*)gpa,
                (__attribute__((address_space(3))) void*)(As + (w * 128 + j * 64) * 8),
                16, 0, 0);
            __builtin_amdgcn_global_load_lds(
                (const __attribute__((address_space(1))) void*)gpb,
                (__attribute__((address_space(3))) void*)(Bs + (w * 128 + j * 64) * 8),
                16, 0, 0);
        }
        __syncthreads();

        bf16x8 af[4], bf[4];
        #pragma unroll
        for (int mt = 0; mt < 4; ++mt)
            af[mt] = *(const bf16x8*)&As[(wm * 64 + mt * 16 + lm) * 32 + lq * 8];
        #pragma unroll
        for (int nt = 0; nt < 4; ++nt)
            bf[nt] = *(const bf16x8*)&Bs[(wn * 64 + nt * 16 + lm) * 32 + lq * 8];

        #pragma unroll
        for (int mt = 0; mt < 4; ++mt)
            #pragma unroll
            for (int nt = 0; nt < 4; ++nt)
                acc[mt][nt] = __builtin_amdgcn_mfma_f32_16x16x32_bf16(
                    af[mt], bf[nt], acc[mt][nt], 0, 0, 0);

        __syncthreads();
    }

    // C write: chunk-major [gn>>5][gm][gn&31]
    #pragma unroll
    for (int mt = 0; mt < 4; ++mt) {
        #pragma unroll
        for (int r = 0; r < 4; ++r) {
            int gm = m0 + wm * 64 + mt * 16 + lq * 4 + r;
            if (gm < M) {
                #pragma unroll
                for (int nt = 0; nt < 4; ++nt) {
                    int gn = n0 + wn * 64 + nt * 16 + lm;
                    C[(size_t)(gn >> 5) * (size_t)M * 32 + (size_t)gm * 32 + (gn & 31)]
                        = f2bf_rne(acc[mt][nt][r]);
                }
            }
        }
    }
}

// ---------------- XCD column-sliced aggregation ----------------------------
// chunk = blockIdx%8 (mod NCH): under round-robin dispatch, each XCD works on
// ONE 32-col chunk whose [n_nodes x 32] bf16 slice (3.2MB / 1.6MB) is
// contiguous and L2-resident. 8 lanes x 8B cover a 64B chunk-row; grp =
// lane>>3 picks the edge, so one wave load gathers 8 independent edges.
// Two banks in flight (16 edges); butterfly merge over groups at the end.

__device__ __forceinline__ void upd4(float* a, uint2 p, float w) {
    a[0] = fmaf(bf_lo(p.x), w, a[0]);
    a[1] = fmaf(bf_hi(p.x), w, a[1]);
    a[2] = fmaf(bf_lo(p.y), w, a[2]);
    a[3] = fmaf(bf_hi(p.y), w, a[3]);
}

template <int D, bool RELU, bool OUTBF>
__global__ __launch_bounds__(256) void aggregate_sliced(const u16* __restrict__ x,
                                                        const int* __restrict__ row_ptr,
                                                        const long long* __restrict__ edata,
                                                        const float* __restrict__ dinv,
                                                        const float* __restrict__ bias,
                                                        void* __restrict__ outp, int n_nodes) {
    constexpr int NCH = D / 32;      // chunks: 8 (D=256) or 4 (D=128)
    constexpr int NSL = 8 / NCH;     // node sub-slices per bid-octet

    const int slot  = blockIdx.x & 7;
    const int chunk = slot & (NCH - 1);
    const int wv    = threadIdx.x >> 6;
    const int lane  = threadIdx.x & 63;
    const int grp   = lane >> 3;     // edge group 0..7
    const int l     = lane & 7;      // 4 cols (8B) within the 32-col chunk
    const int nb    = (int)(blockIdx.x >> 3) * (32 * NSL) + (slot / NCH) * 32 + wv * 8;

    const u16* __restrict__ xc = x + (size_t)chunk * (size_t)n_nodes * 32;
    const float4 bch = *(const float4*)(bias + chunk * 32 + l * 4);

    for (int r = 0; r < 8; ++r) {
        const int node = nb + r;
        if (node >= n_nodes) return;

        const float di = dinv[node];
        const int e0 = row_ptr[node], e1 = row_ptr[node + 1];

        float a0[4], a1[4];
        {
            // self loop (grp 0 contributes; others weight 0)
            uint2 ps = *(const uint2*)(xc + (size_t)node * 32 + l * 4);
            float w = (grp == 0) ? di * di : 0.0f;
            a0[0] = bf_lo(ps.x) * w; a0[1] = bf_hi(ps.x) * w;
            a0[2] = bf_lo(ps.y) * w; a0[3] = bf_hi(ps.y) * w;
            a1[0] = 0.0f; a1[1] = 0.0f; a1[2] = 0.0f; a1[3] = 0.0f;
        }

        int e = e0;
        for (; e + 16 <= e1; e += 16) {
            long long q0 = __builtin_nontemporal_load(&edata[e + grp]);
            long long q1 = __builtin_nontemporal_load(&edata[e + 8 + grp]);
            uint2 p0 = *(const uint2*)(xc + (size_t)(int)q0 * 32 + l * 4);
            uint2 p1 = *(const uint2*)(xc + (size_t)(int)q1 * 32 + l * 4);
            upd4(a0, p0, __int_as_float((int)(q0 >> 32)));
            upd4(a1, p1, __int_as_float((int)(q1 >> 32)));
        }
        for (; e < e1; e += 8) {
            int ee = e + grp;
            long long q = 0;                       // col 0, weight +0.0 -> no-op
            if (ee < e1) q = __builtin_nontemporal_load(&edata[ee]);
            uint2 p = *(const uint2*)(xc + (size_t)(int)q * 32 + l * 4);
            upd4(a0, p, __int_as_float((int)(q >> 32)));
        }

        float v[4];
        #pragma unroll
        for (int j = 0; j < 4; ++j) v[j] = a0[j] + a1[j];
        #pragma unroll
        for (int m = 8; m < 64; m <<= 1)
            #pragma unroll
            for (int j = 0; j < 4; ++j) v[j] += __shfl_xor(v[j], m, 64);

        if (grp == 0) {
            v[0] += bch.x; v[1] += bch.y; v[2] += bch.z; v[3] += bch.w;
            if (RELU) {
                #pragma unroll
                for (int j = 0; j < 4; ++j) v[j] = fmaxf(v[j], 0.0f);
            }
            if constexpr (OUTBF) {
                // chunk-major bf16 out (feeds gemm2 / next agg)
                u16* op = (u16*)outp + (size_t)chunk * (size_t)n_nodes * 32
                                      + (size_t)node * 32 + l * 4;
                uint2 pk;
                pk.x = (uint32)f2bf_rne(v[0]) | ((uint32)f2bf_rne(v[1]) << 16);
                pk.y = (uint32)f2bf_rne(v[2]) | ((uint32)f2bf_rne(v[3]) << 16);
                *(uint2*)op = pk;
            } else {
                // final output: row-major f32
                float* op = (float*)outp + (size_t)node * D + chunk * 32 + l * 4;
                *(float4*)op = make_float4(v[0], v[1], v[2], v[3]);
            }
        }
    }
}

// ---------------- launcher ----------------

extern "C" void kernel_launch(void* const* d_in, const int* in_sizes, int n_in,
                              void* d_out, int out_size, void* d_ws, size_t ws_size,
                              hipStream_t stream) {
    const float* z  = (const float*)d_in[0];
    const int*   ei = (const int*)d_in[1];
    const float* W1 = (const float*)d_in[2];
    const float* b1 = (const float*)d_in[3];
    const float* W2 = (const float*)d_in[4];
    const float* b2 = (const float*)d_in[5];
    float* out = (float*)d_out;

    const int Nn = N_NODES, E = N_EDGES;
    const int* srcp = ei;
    const int* dstp = ei + E;

    char* ws = (char*)d_ws;
    size_t off = 0;
    auto alloc = [&](size_t bytes) -> char* {
        char* p = ws + off;
        off += (bytes + 511) & ~(size_t)511;
        return p;
    };
    u16*   zb     = (u16*)  alloc((size_t)Nn * D_IN * 2);
    u16*   w1t    = (u16*)  alloc((size_t)D_IN * D_HID * 2);
    u16*   w2t    = (u16*)  alloc((size_t)D_HID * D_OUT * 2);
    u16*   x1b    = (u16*)  alloc((size_t)Nn * D_HID * 2);   // chunk-major
    u16*   hb     = (u16*)  alloc((size_t)Nn * D_HID * 2);   // chunk-major
    u16*   h2b    = (u16*)  alloc((size_t)Nn * D_OUT * 2);   // chunk-major
    int*   cnt    = (int*)  alloc((size_t)Nn * 4);
    float* dinv   = (float*)alloc((size_t)Nn * 4);
    int*   row_ptr= (int*)  alloc((size_t)(Nn + 1) * 4);
    int*   rank   = (int*)  alloc((size_t)E * 4);
    int2*  edata  = (int2*) alloc((size_t)E * 8);

    hipMemsetAsync(cnt, 0, (size_t)Nn * 4, stream);
    prep_kernel<<<1024, 256, 0, stream>>>(z, dstp, W1, W2, zb, w1t, w2t, cnt, rank);
    scan_kernel<<<1, 1024, 0, stream>>>(cnt, dinv, row_ptr, Nn);
    fill_kernel<<<(E + 255) / 256, 256, 0, stream>>>(srcp, dstp, rank, row_ptr, dinv, edata, E);
    {
        dim3 grid((Nn + 127) / 128, D_HID / 128);
        gemm_bf16_kernel<D_HID, false><<<grid, 256, 0, stream>>>(zb, w1t, x1b, Nn);
    }
    {
        int blocks = ((Nn + 31) / 32) * 8;            // 12504: chunk = bid%8
        aggregate_sliced<D_HID, true, true><<<blocks, 256, 0, stream>>>(
            x1b, row_ptr, (const long long*)edata, dinv, b1, hb, Nn);
    }
    {
        dim3 grid((Nn + 127) / 128, D_OUT / 128);
        gemm_bf16_kernel<D_OUT, true><<<grid, 256, 0, stream>>>(hb, w2t, h2b, Nn);
    }
    {
        int blocks = ((Nn + 63) / 64) * 8;            // 6256: 4 chunks x 2 slices
        aggregate_sliced<D_OUT, false, false><<<blocks, 256, 0, stream>>>(
            h2b, row_ptr, (const long long*)edata, dinv, b2, out, Nn);
    }
}